// Round 1
// baseline (1765.962 us; speedup 1.0000x reference)
//
#include <hip/hip_runtime.h>
#include <stdint.h>

typedef unsigned short u16;
typedef __bf16 bf16x8 __attribute__((ext_vector_type(8)));
typedef float f32x4 __attribute__((ext_vector_type(4)));

#define BDIM 16
#define SLEN 512
#define DMODEL 1024
#define NHEAD 16
#define DHEAD 64
#define FDIM 4096
#define NLAYER 4
#define ROWS (BDIM*SLEN)   // 8192

// f32 -> bf16 round-to-nearest-even
__device__ __forceinline__ u16 f2b(float f) {
  uint32_t u = __builtin_bit_cast(uint32_t, f);
  u = (u + 0x7fffu + ((u >> 16) & 1u)) >> 16;
  return (u16)u;
}

// async global->LDS, 16B per lane. LDS dest is WAVE-UNIFORM base (+lane*16 by HW);
// global src is per-lane. Casts via uintptr avoid addrspacecast portability issues
// (low 32 bits of a generic LDS pointer are the LDS byte offset on gfx9+).
__device__ __forceinline__ void gl_lds16(const void* g, void* l) {
  uint32_t loff = (uint32_t)(uintptr_t)l;
  __builtin_amdgcn_global_load_lds(
      (__attribute__((address_space(1))) uint32_t*)(uintptr_t)g,
      (__attribute__((address_space(3))) uint32_t*)loff,
      16, 0, 0);
}

// ---------------- prep: x = q + pe (f32 + bf16), y = qa + pe (bf16) ----------------
__global__ __launch_bounds__(256) void prep_kernel(const float4* __restrict__ q,
                                                   const float4* __restrict__ qa,
                                                   const float4* __restrict__ pe,
                                                   float4* __restrict__ x,
                                                   u16* __restrict__ xb,
                                                   u16* __restrict__ yb) {
  int idx = blockIdx.x * 256 + threadIdx.x;          // ROWS*DMODEL/4 threads
  int pidx = idx & (SLEN * DMODEL / 4 - 1);          // broadcast over batch (S*D pow2)
  float4 qv = q[idx], av = qa[idx], pv = pe[pidx];
  float4 xv = make_float4(qv.x + pv.x, qv.y + pv.y, qv.z + pv.z, qv.w + pv.w);
  float4 yv = make_float4(av.x + pv.x, av.y + pv.y, av.z + pv.z, av.w + pv.w);
  x[idx] = xv;
  uint32_t x0 = (uint32_t)f2b(xv.x) | ((uint32_t)f2b(xv.y) << 16);
  uint32_t x1 = (uint32_t)f2b(xv.z) | ((uint32_t)f2b(xv.w) << 16);
  uint32_t y0 = (uint32_t)f2b(yv.x) | ((uint32_t)f2b(yv.y) << 16);
  uint32_t y1 = (uint32_t)f2b(yv.z) | ((uint32_t)f2b(yv.w) << 16);
  ((uint2*)xb)[idx] = make_uint2(x0, x1);
  ((uint2*)yb)[idx] = make_uint2(y0, y1);
}

// ---------------- transpose f32 [M][N] -> bf16 [N][M] ----------------
__global__ __launch_bounds__(256) void transpose_f2b(const float* __restrict__ in,
                                                     u16* __restrict__ out,
                                                     int M, int N) {
  __shared__ float t[32][33];
  int tx = threadIdx.x & 31, ty = threadIdx.x >> 5;
  int m0 = blockIdx.y * 32, n0 = blockIdx.x * 32;
  #pragma unroll
  for (int i = 0; i < 32; i += 8) t[ty + i][tx] = in[(size_t)(m0 + ty + i) * N + n0 + tx];
  __syncthreads();
  #pragma unroll
  for (int i = 0; i < 32; i += 8) out[(size_t)(n0 + ty + i) * M + m0 + tx] = f2b(t[tx][ty + i]);
}

// ---------------- GEMM: C[M][N] = A[M][K] @ B + bias, B given transposed BT[N][K] ----------------
// 128x128 tile, BK=32, 4 waves (2x2 of 64x64), mfma_f32_16x16x32_bf16, global_load_lds staging.
template<bool RELU, bool BF16OUT>
__global__ __launch_bounds__(256) void gemm_bt(const u16* __restrict__ A,
                                               const u16* __restrict__ BT,
                                               const float* __restrict__ bias,
                                               void* __restrict__ C,
                                               int M, int N, int K) {
  __shared__ __attribute__((aligned(16))) u16 As[128 * 32];
  __shared__ __attribute__((aligned(16))) u16 Bs[128 * 32];
  const int tid = threadIdx.x, wave = tid >> 6, lane = tid & 63;
  const int lg = lane >> 4, lc = lane & 15;
  const int wr = wave >> 1, wc = wave & 1;
  const int m0 = blockIdx.y * 128, n0 = blockIdx.x * 128;
  const char* Ab = (const char*)A + (size_t)m0 * K * 2;
  const char* Bb = (const char*)BT + (size_t)n0 * K * 2;
  const size_t ldb = (size_t)K * 2;   // row stride bytes
  f32x4 zero4 = {0.f, 0.f, 0.f, 0.f};
  f32x4 acc[4][4];
  #pragma unroll
  for (int m = 0; m < 4; m++)
    #pragma unroll
    for (int n = 0; n < 4; n++) acc[m][n] = zero4;

  for (int kt = 0; kt < K; kt += 32) {
    __syncthreads();   // previous compute done before overwrite (drains vmcnt/lgkm)
    #pragma unroll
    for (int c = 0; c < 2; c++) {
      int o = wave * 1024 + c * 4096 + lane * 16;   // linear byte offset in 8KB tile
      int row = o >> 6, colb = o & 63;              // 64B per tile row (BK=32 bf16)
      gl_lds16(Ab + (size_t)row * ldb + kt * 2 + colb, (char*)As + wave * 1024 + c * 4096);
      gl_lds16(Bb + (size_t)row * ldb + kt * 2 + colb, (char*)Bs + wave * 1024 + c * 4096);
    }
    __syncthreads();   // staging visible
    bf16x8 af[4], bfr[4];
    #pragma unroll
    for (int m = 0; m < 4; m++)
      af[m] = *(const bf16x8*)&As[(wr * 64 + m * 16 + lc) * 32 + lg * 8];
    #pragma unroll
    for (int n = 0; n < 4; n++)
      bfr[n] = *(const bf16x8*)&Bs[(wc * 64 + n * 16 + lc) * 32 + lg * 8];
    #pragma unroll
    for (int m = 0; m < 4; m++)
      #pragma unroll
      for (int n = 0; n < 4; n++)
        acc[m][n] = __builtin_amdgcn_mfma_f32_16x16x32_bf16(af[m], bfr[n], acc[m][n], 0, 0, 0);
  }

  // epilogue: C row = (lane>>4)*4+reg, col = lane&15 (m89-verified layout)
  #pragma unroll
  for (int m = 0; m < 4; m++) {
    int row = m0 + wr * 64 + m * 16 + lg * 4;
    #pragma unroll
    for (int n = 0; n < 4; n++) {
      int col = n0 + wc * 64 + n * 16 + lc;
      float bv = bias[col];
      #pragma unroll
      for (int r = 0; r < 4; r++) {
        float v = acc[m][n][r] + bv;
        if (RELU) v = fmaxf(v, 0.f);
        if (BF16OUT) ((u16*)C)[(size_t)(row + r) * N + col] = f2b(v);
        else         ((float*)C)[(size_t)(row + r) * N + col] = v;
      }
    }
  }
}

// ---------------- flash attention (strict causal, kq_same) ----------------
// grid: (S/64, B*H). Block = 4 waves; wave w owns q-rows [64*qt + 16w, +16).
__global__ __launch_bounds__(256) void attn_kernel(const u16* __restrict__ QK,
                                                   const u16* __restrict__ V,
                                                   u16* __restrict__ CTX) {
  __shared__ __attribute__((aligned(16))) u16 Qs[64 * 64];
  __shared__ __attribute__((aligned(16))) u16 Ks[64 * 64];
  __shared__ __attribute__((aligned(16))) u16 VTs[64 * 72];   // VT[d][s], row pad 72 (16B-aligned b128)
  __shared__ __attribute__((aligned(16))) u16 Ps[4][16 * 72]; // per-wave P[qrow][key]
  const int qt = blockIdx.x, bh = blockIdx.y;
  const int b = bh >> 4, h = bh & 15;
  const char* Qg = (const char*)(QK + (size_t)b * SLEN * DMODEL + h * DHEAD);
  const char* Vg = (const char*)(V + (size_t)b * SLEN * DMODEL + h * DHEAD);
  const int tid = threadIdx.x, wave = tid >> 6, lane = tid & 63;
  const int lg = lane >> 4, lc = lane & 15;

  // stage Q tile (64 rows x 64 dk = 8KB), row stride D
  #pragma unroll
  for (int c = 0; c < 2; c++) {
    int o = wave * 1024 + c * 4096 + lane * 16;
    int row = o >> 7, colb = o & 127;
    gl_lds16(Qg + (size_t)(qt * 64 + row) * (DMODEL * 2) + colb, (char*)Qs + wave * 1024 + c * 4096);
  }

  float m_run[4], l_run[4];
  f32x4 zero4 = {0.f, 0.f, 0.f, 0.f};
  f32x4 acc_o[4];
  #pragma unroll
  for (int r = 0; r < 4; r++) { m_run[r] = -1e30f; l_run[r] = 0.f; }
  #pragma unroll
  for (int n = 0; n < 4; n++) acc_o[n] = zero4;

  for (int kt = 0; kt <= qt; kt++) {
    __syncthreads();   // prev iter reads done; also drains Q/K staging vmcnt
    #pragma unroll
    for (int c = 0; c < 2; c++) {
      int o = wave * 1024 + c * 4096 + lane * 16;
      int row = o >> 7, colb = o & 127;
      gl_lds16(Qg + (size_t)(kt * 64 + row) * (DMODEL * 2) + colb, (char*)Ks + wave * 1024 + c * 4096);
    }
    { // stage V transposed: VT[d][s]
      int s = tid >> 2, c0 = (tid & 3) * 16;
      const u16* vr = (const u16*)(Vg + (size_t)(kt * 64 + s) * (DMODEL * 2)) + c0;
      uint4 u0 = *(const uint4*)vr;
      uint4 u1 = *(const uint4*)(vr + 8);
      u16 e[16];
      *(uint4*)&e[0] = u0; *(uint4*)&e[8] = u1;
      #pragma unroll
      for (int j = 0; j < 16; j++) VTs[(c0 + j) * 72 + s] = e[j];
    }
    __syncthreads();

    // QK^T: S[16 q-rows][64 keys] for this wave
    f32x4 sc[4];
    #pragma unroll
    for (int n = 0; n < 4; n++) sc[n] = zero4;
    #pragma unroll
    for (int k0 = 0; k0 < 64; k0 += 32) {
      bf16x8 aq = *(const bf16x8*)&Qs[(wave * 16 + lc) * 64 + k0 + lg * 8];
      #pragma unroll
      for (int n = 0; n < 4; n++) {
        bf16x8 bk_ = *(const bf16x8*)&Ks[(n * 16 + lc) * 64 + k0 + lg * 8];
        sc[n] = __builtin_amdgcn_mfma_f32_16x16x32_bf16(aq, bk_, sc[n], 0, 0, 0);
      }
    }

    // mask (key < query strictly) + online softmax. Lane holds rows lg*4+r, col n*16+lc.
    float pm[4][4], rmax[4];
    #pragma unroll
    for (int r = 0; r < 4; r++) rmax[r] = -1e30f;
    #pragma unroll
    for (int n = 0; n < 4; n++)
      #pragma unroll
      for (int r = 0; r < 4; r++) {
        int qg = qt * 64 + wave * 16 + lg * 4 + r;
        int kg = kt * 64 + n * 16 + lc;
        float s_ = (kg < qg) ? sc[n][r] * 0.125f : -1e30f;
        pm[n][r] = s_;
        rmax[r] = fmaxf(rmax[r], s_);
      }
    #pragma unroll
    for (int d = 1; d < 16; d <<= 1)
      #pragma unroll
      for (int r = 0; r < 4; r++) rmax[r] = fmaxf(rmax[r], __shfl_xor(rmax[r], d, 64));
    float corr[4];
    #pragma unroll
    for (int r = 0; r < 4; r++) {
      float mn = fmaxf(m_run[r], rmax[r]);
      corr[r] = __expf(m_run[r] - mn);
      m_run[r] = mn;
    }
    float rsum[4] = {0.f, 0.f, 0.f, 0.f};
    #pragma unroll
    for (int n = 0; n < 4; n++)
      #pragma unroll
      for (int r = 0; r < 4; r++) {
        float p = __expf(pm[n][r] - m_run[r]);
        pm[n][r] = p; rsum[r] += p;
      }
    #pragma unroll
    for (int d = 1; d < 16; d <<= 1)
      #pragma unroll
      for (int r = 0; r < 4; r++) rsum[r] += __shfl_xor(rsum[r], d, 64);
    #pragma unroll
    for (int r = 0; r < 4; r++) l_run[r] = l_run[r] * corr[r] + rsum[r];
    #pragma unroll
    for (int n = 0; n < 4; n++)
      #pragma unroll
      for (int r = 0; r < 4; r++) acc_o[n][r] *= corr[r];

    // P -> LDS (wave-private), then PV
    #pragma unroll
    for (int n = 0; n < 4; n++)
      #pragma unroll
      for (int r = 0; r < 4; r++) Ps[wave][(lg * 4 + r) * 72 + n * 16 + lc] = f2b(pm[n][r]);
    __asm__ volatile("s_waitcnt lgkmcnt(0)" ::: "memory");
    #pragma unroll
    for (int k0 = 0; k0 < 64; k0 += 32) {
      bf16x8 ap = *(const bf16x8*)&Ps[wave][lc * 72 + k0 + lg * 8];
      #pragma unroll
      for (int n = 0; n < 4; n++) {
        bf16x8 bv_ = *(const bf16x8*)&VTs[(n * 16 + lc) * 72 + k0 + lg * 8];
        acc_o[n] = __builtin_amdgcn_mfma_f32_16x16x32_bf16(ap, bv_, acc_o[n], 0, 0, 0);
      }
    }
  }

  // write ctx (row 0 of each sequence is zeroed, matching row_keep)
  #pragma unroll
  for (int n = 0; n < 4; n++)
    #pragma unroll
    for (int r = 0; r < 4; r++) {
      int sq = qt * 64 + wave * 16 + lg * 4 + r;
      float v = (sq == 0) ? 0.f : acc_o[n][r] / l_run[r];
      CTX[((size_t)b * SLEN + sq) * DMODEL + h * DHEAD + n * 16 + lc] = f2b(v);
    }
}

// ---------------- fused residual + LayerNorm ----------------
__global__ __launch_bounds__(256) void ln_kernel(const float* __restrict__ tmp,
                                                 float* __restrict__ x,
                                                 u16* __restrict__ xb,
                                                 const float* __restrict__ gw,
                                                 const float* __restrict__ bw) {
  __shared__ float red[4], red2[4];
  const int row = blockIdx.x, t = threadIdx.x;
  const size_t base = (size_t)row * DMODEL;
  float v[4];
  #pragma unroll
  for (int i = 0; i < 4; i++) v[i] = x[base + t + i * 256] + tmp[base + t + i * 256];
  float s = v[0] + v[1] + v[2] + v[3];
  #pragma unroll
  for (int d = 1; d < 64; d <<= 1) s += __shfl_xor(s, d, 64);
  if ((t & 63) == 0) red[t >> 6] = s;
  __syncthreads();
  float mean = (red[0] + red[1] + red[2] + red[3]) * (1.f / DMODEL);
  float q2 = 0.f;
  #pragma unroll
  for (int i = 0; i < 4; i++) { float d_ = v[i] - mean; q2 += d_ * d_; }
  #pragma unroll
  for (int d = 1; d < 64; d <<= 1) q2 += __shfl_xor(q2, d, 64);
  if ((t & 63) == 0) red2[t >> 6] = q2;
  __syncthreads();
  float var = (red2[0] + red2[1] + red2[2] + red2[3]) * (1.f / DMODEL);
  float rs = rsqrtf(var + 1e-5f);
  #pragma unroll
  for (int i = 0; i < 4; i++) {
    int col = t + i * 256;
    float o = (v[i] - mean) * rs * gw[col] + bw[col];
    x[base + col] = o;
    xb[base + col] = f2b(o);
  }
}

__global__ __launch_bounds__(256) void copy_f4(const float4* __restrict__ src, float4* __restrict__ dst) {
  int i = blockIdx.x * 256 + threadIdx.x;
  dst[i] = src[i];
}

extern "C" void kernel_launch(void* const* d_in, const int* in_sizes, int n_in,
                              void* d_out, int out_size, void* d_ws, size_t ws_size,
                              hipStream_t stream) {
  (void)in_sizes; (void)n_in; (void)out_size; (void)ws_size;
  const float* q    = (const float*)d_in[0];
  const float* qa   = (const float*)d_in[1];
  const float* pe   = (const float*)d_in[2];
  const float* Wk   = (const float*)d_in[3];
  const float* bk   = (const float*)d_in[4];
  const float* Wv   = (const float*)d_in[5];
  const float* bv   = (const float*)d_in[6];
  const float* Wo   = (const float*)d_in[7];
  const float* bo   = (const float*)d_in[8];
  const float* ln1g = (const float*)d_in[9];
  const float* ln1b = (const float*)d_in[10];
  const float* W1   = (const float*)d_in[11];
  const float* b1   = (const float*)d_in[12];
  const float* W2   = (const float*)d_in[13];
  const float* b2   = (const float*)d_in[14];
  const float* ln2g = (const float*)d_in[15];
  const float* ln2b = (const float*)d_in[16];

  char* w = (char*)d_ws;
  float* x_f32 = (float*)w; w += (size_t)ROWS * DMODEL * 4;
  u16* xb   = (u16*)w; w += (size_t)ROWS * DMODEL * 2;
  u16* yb   = (u16*)w; w += (size_t)ROWS * DMODEL * 2;
  u16* qkb  = (u16*)w; w += (size_t)ROWS * DMODEL * 2;
  u16* vb   = (u16*)w; w += (size_t)ROWS * DMODEL * 2;
  u16* ctxb = (u16*)w; w += (size_t)ROWS * DMODEL * 2;
  u16* ffnb = (u16*)w; w += (size_t)ROWS * FDIM * 2;
  u16* WkT  = (u16*)w; w += (size_t)DMODEL * DMODEL * 2;
  u16* WvT  = (u16*)w; w += (size_t)DMODEL * DMODEL * 2;
  u16* WoT  = (u16*)w; w += (size_t)DMODEL * DMODEL * 2;
  u16* W1T  = (u16*)w; w += (size_t)DMODEL * FDIM * 2;
  u16* W2T  = (u16*)w; w += (size_t)DMODEL * FDIM * 2;
  float* tmpf = (float*)qkb;  // alias qkb+vb (both dead when tmpf is written); 33.5MB

  prep_kernel<<<ROWS * DMODEL / 4 / 256, 256, 0, stream>>>(
      (const float4*)q, (const float4*)qa, (const float4*)pe, (float4*)x_f32, xb, yb);

  for (int l = 0; l < NLAYER; l++) {
    transpose_f2b<<<dim3(32, 32), 256, 0, stream>>>(Wk + (size_t)l * DMODEL * DMODEL, WkT, DMODEL, DMODEL);
    transpose_f2b<<<dim3(32, 32), 256, 0, stream>>>(Wv + (size_t)l * DMODEL * DMODEL, WvT, DMODEL, DMODEL);
    transpose_f2b<<<dim3(32, 32), 256, 0, stream>>>(Wo + (size_t)l * DMODEL * DMODEL, WoT, DMODEL, DMODEL);
    transpose_f2b<<<dim3(128, 32), 256, 0, stream>>>(W1 + (size_t)l * DMODEL * FDIM, W1T, DMODEL, FDIM);
    transpose_f2b<<<dim3(32, 128), 256, 0, stream>>>(W2 + (size_t)l * FDIM * DMODEL, W2T, FDIM, DMODEL);

    gemm_bt<false, true><<<dim3(DMODEL / 128, ROWS / 128), 256, 0, stream>>>(
        xb, WkT, bk + l * DMODEL, qkb, ROWS, DMODEL, DMODEL);
    gemm_bt<false, true><<<dim3(DMODEL / 128, ROWS / 128), 256, 0, stream>>>(
        yb, WvT, bv + l * DMODEL, vb, ROWS, DMODEL, DMODEL);
    attn_kernel<<<dim3(SLEN / 64, BDIM * NHEAD), 256, 0, stream>>>(qkb, vb, ctxb);
    gemm_bt<false, false><<<dim3(DMODEL / 128, ROWS / 128), 256, 0, stream>>>(
        ctxb, WoT, bo + l * DMODEL, tmpf, ROWS, DMODEL, DMODEL);
    ln_kernel<<<ROWS, 256, 0, stream>>>(tmpf, x_f32, xb, ln1g + l * DMODEL, ln1b + l * DMODEL);
    gemm_bt<true, true><<<dim3(FDIM / 128, ROWS / 128), 256, 0, stream>>>(
        xb, W1T, b1 + l * FDIM, ffnb, ROWS, FDIM, DMODEL);
    gemm_bt<false, false><<<dim3(DMODEL / 128, ROWS / 128), 256, 0, stream>>>(
        ffnb, W2T, b2 + l * DMODEL, tmpf, ROWS, DMODEL, FDIM);
    ln_kernel<<<ROWS, 256, 0, stream>>>(tmpf, x_f32, xb, ln2g + l * DMODEL, ln2b + l * DMODEL);
  }
  copy_f4<<<ROWS * DMODEL / 4 / 256, 256, 0, stream>>>((const float4*)x_f32, (float4*)d_out);
}

// Round 2
// 1396.439 us; speedup vs baseline: 1.2646x; 1.2646x over previous
//
#include <hip/hip_runtime.h>
#include <stdint.h>

typedef unsigned short u16;
typedef __bf16 bf16x8 __attribute__((ext_vector_type(8)));
typedef float f32x4 __attribute__((ext_vector_type(4)));

#define BDIM 16
#define SLEN 512
#define DMODEL 1024
#define NHEAD 16
#define DHEAD 64
#define FDIM 4096
#define NLAYER 4
#define ROWS (BDIM*SLEN)   // 8192

// f32 -> bf16 round-to-nearest-even
__device__ __forceinline__ u16 f2b(float f) {
  uint32_t u = __builtin_bit_cast(uint32_t, f);
  u = (u + 0x7fffu + ((u >> 16) & 1u)) >> 16;
  return (u16)u;
}

// async global->LDS, 16B per lane. LDS dest is WAVE-UNIFORM base (+lane*16 by HW);
// global src is per-lane (this is how we realize the swizzled LDS layout).
__device__ __forceinline__ void gl_lds16(const void* g, void* l) {
  uint32_t loff = (uint32_t)(uintptr_t)l;
  __builtin_amdgcn_global_load_lds(
      (__attribute__((address_space(1))) uint32_t*)(uintptr_t)g,
      (__attribute__((address_space(3))) uint32_t*)loff,
      16, 0, 0);
}

// ---------------- prep: x = q + pe (f32 + bf16), y = qa + pe (bf16) ----------------
__global__ __launch_bounds__(256) void prep_kernel(const float4* __restrict__ q,
                                                   const float4* __restrict__ qa,
                                                   const float4* __restrict__ pe,
                                                   float4* __restrict__ x,
                                                   u16* __restrict__ xb,
                                                   u16* __restrict__ yb) {
  int idx = blockIdx.x * 256 + threadIdx.x;
  int pidx = idx & (SLEN * DMODEL / 4 - 1);
  float4 qv = q[idx], av = qa[idx], pv = pe[pidx];
  float4 xv = make_float4(qv.x + pv.x, qv.y + pv.y, qv.z + pv.z, qv.w + pv.w);
  float4 yv = make_float4(av.x + pv.x, av.y + pv.y, av.z + pv.z, av.w + pv.w);
  x[idx] = xv;
  uint32_t x0 = (uint32_t)f2b(xv.x) | ((uint32_t)f2b(xv.y) << 16);
  uint32_t x1 = (uint32_t)f2b(xv.z) | ((uint32_t)f2b(xv.w) << 16);
  uint32_t y0 = (uint32_t)f2b(yv.x) | ((uint32_t)f2b(yv.y) << 16);
  uint32_t y1 = (uint32_t)f2b(yv.z) | ((uint32_t)f2b(yv.w) << 16);
  ((uint2*)xb)[idx] = make_uint2(x0, x1);
  ((uint2*)yb)[idx] = make_uint2(y0, y1);
}

// ---------------- transpose f32 [M][N] -> bf16 [N][M] ----------------
__global__ __launch_bounds__(256) void transpose_f2b(const float* __restrict__ in,
                                                     u16* __restrict__ out,
                                                     int M, int N) {
  __shared__ float t[32][33];
  int tx = threadIdx.x & 31, ty = threadIdx.x >> 5;
  int m0 = blockIdx.y * 32, n0 = blockIdx.x * 32;
  #pragma unroll
  for (int i = 0; i < 32; i += 8) t[ty + i][tx] = in[(size_t)(m0 + ty + i) * N + n0 + tx];
  __syncthreads();
  #pragma unroll
  for (int i = 0; i < 32; i += 8) out[(size_t)(n0 + ty + i) * M + m0 + tx] = f2b(t[tx][ty + i]);
}

// ---------------- 8-phase 256xBN GEMM: C[M][N] = A[M][K] @ B + bias, B as BT[N][K] ----------------
// 8 waves (2M x 4N), BK=64, 2 LDS K-tile buffers, 1 half-tile staged per phase,
// counted vmcnt(4) only at phases 4/8 (derived from the stage/consume schedule),
// granule-rotate LDS layout (conflict-free ds_read_b128), setprio around MFMA.
template<int BN, bool RELU, bool BF16OUT>
__global__ __launch_bounds__(512, 2) void gemm8p(const u16* __restrict__ Ap,
                                                 const u16* __restrict__ Bp,
                                                 const float* __restrict__ bias,
                                                 void* __restrict__ Cp,
                                                 int M, int N, int K) {
  constexpr int NBH = BN / 128;          // B half-tiles per K-tile (1 or 2)
  constexpr int NREP = BN / 64;          // n-frags per wave (2 or 4)
  constexpr int QN = NREP / 2;           // n-frags per quadrant (1 or 2)
  constexpr int HU = 8192;               // u16 per 16KB half-tile
  __shared__ __attribute__((aligned(16))) u16 lds[2][(2 + NBH) * HU];

  const int tid = threadIdx.x, wave = tid >> 6, lane = tid & 63;
  const int lg = lane >> 4, lc = lane & 15;
  const int wm = wave >> 2, wn = wave & 3;

  // bijective XCD swizzle (m204 variant)
  const int gx = gridDim.x;
  int nwg = gx * gridDim.y;
  int orig = blockIdx.y * gx + blockIdx.x;
  int qq = nwg >> 3, rr_ = nwg & 7;
  int xcd = orig & 7, ix = orig >> 3;
  int wg = (xcd < rr_ ? xcd * (qq + 1) : rr_ * (qq + 1) + (xcd - rr_) * qq) + ix;
  const int m0 = (wg / gx) * 256, n0 = (wg % gx) * BN;

  const int ldbyte = K * 2;
  const char* Ag = (const char*)Ap + (size_t)m0 * ldbyte;
  const char* Bg = (const char*)Bp + (size_t)n0 * ldbyte;

  // per-lane pre-permuted source offsets: LDS slot (row r, 16B-col c) holds granule g=(c-r)&7
  int o1 = tid * 16, o2 = 8192 + tid * 16;
  int sr1 = o1 >> 7, sg1 = (((o1 >> 4) & 7) - sr1) & 7;
  int sr2 = o2 >> 7, sg2 = (((o2 >> 4) & 7) - sr2) & 7;
  const int soff1 = sr1 * ldbyte + sg1 * 16;
  const int soff2 = sr2 * ldbyte + sg2 * 16;
  const int NT = K >> 6;

  auto stageA = [&](int kt, int h, int buf) {
    const char* g = Ag + (size_t)h * 128 * ldbyte + (size_t)kt * 128;
    char* d = (char*)&lds[buf][h * HU] + wave * 1024;
    gl_lds16(g + soff1, d);
    gl_lds16(g + soff2, d + 8192);
  };
  auto stageB = [&](int kt, int h, int buf) {
    const char* g = Bg + (size_t)h * 128 * ldbyte + (size_t)kt * 128;
    char* d = (char*)&lds[buf][(2 + h) * HU] + wave * 1024;
    gl_lds16(g + soff1, d);
    gl_lds16(g + soff2, d + 8192);
  };

  const int bstart = wn * (BN / 4);
  const int bh = bstart >> 7, bc0 = bstart & 127;

  auto rdA = [&](const u16* base, int f, int kk) -> bf16x8 {
    int row = f * 16 + lc;
    return *(const bf16x8*)&base[row * 64 + (((kk * 4 + lg + row) & 7) << 3)];
  };
  auto rdB = [&](const u16* base, int jj, int kk) -> bf16x8 {
    int row = bc0 + jj * 16 + lc;
    return *(const bf16x8*)&base[row * 64 + (((kk * 4 + lg + row) & 7) << 3)];
  };

  f32x4 acc[8][NREP];
  #pragma unroll
  for (int f = 0; f < 8; f++)
    #pragma unroll
    for (int j = 0; j < NREP; j++) acc[f][j] = (f32x4){0.f, 0.f, 0.f, 0.f};

  // prologue: tile0 fully + tile1's A halves; leave tile1's A (4 loads) in flight
  stageA(0, 0, 0); stageA(0, 1, 0);
  stageB(0, 0, 0); if (NBH == 2) stageB(0, 1, 0);
  stageA(1, 0, 1); stageA(1, 1, 1);
  asm volatile("s_waitcnt vmcnt(4)\n\ts_barrier" ::: "memory");

  auto ktile = [&](int k, int buf) {
    const u16* Ab_ = &lds[buf][wm * HU];
    const u16* Bb_ = &lds[buf][(2 + bh) * HU];
    const int kn = (k + 1 < NT) ? k + 1 : NT - 1;
    const int k2 = (k + 2 < NT) ? k + 2 : NT - 1;
    bf16x8 a0[4][2], a1[4][2], b0[QN][2], b1[QN][2];

    // ---- P1: read A[qm0]+B[qn0]; stage B0(k+1)
    #pragma unroll
    for (int f = 0; f < 4; f++) { a0[f][0] = rdA(Ab_, f, 0); a0[f][1] = rdA(Ab_, f, 1); }
    #pragma unroll
    for (int j = 0; j < QN; j++) { b0[j][0] = rdB(Bb_, j, 0); b0[j][1] = rdB(Bb_, j, 1); }
    stageB(kn, 0, buf ^ 1);
    asm volatile("s_barrier" ::: "memory");
    __builtin_amdgcn_s_setprio(1);
    #pragma unroll
    for (int f = 0; f < 4; f++)
      #pragma unroll
      for (int j = 0; j < QN; j++) {
        acc[f][j] = __builtin_amdgcn_mfma_f32_16x16x32_bf16(a0[f][0], b0[j][0], acc[f][j], 0, 0, 0);
        acc[f][j] = __builtin_amdgcn_mfma_f32_16x16x32_bf16(a0[f][1], b0[j][1], acc[f][j], 0, 0, 0);
      }
    __builtin_amdgcn_s_setprio(0);
    asm volatile("s_barrier" ::: "memory");

    // ---- P2: read A[qm1]; stage B1(k+1)
    #pragma unroll
    for (int f = 0; f < 4; f++) { a1[f][0] = rdA(Ab_, 4 + f, 0); a1[f][1] = rdA(Ab_, 4 + f, 1); }
    if (NBH == 2) stageB(kn, 1, buf ^ 1);
    asm volatile("s_barrier" ::: "memory");
    __builtin_amdgcn_s_setprio(1);
    #pragma unroll
    for (int f = 0; f < 4; f++)
      #pragma unroll
      for (int j = 0; j < QN; j++) {
        acc[4 + f][j] = __builtin_amdgcn_mfma_f32_16x16x32_bf16(a1[f][0], b0[j][0], acc[4 + f][j], 0, 0, 0);
        acc[4 + f][j] = __builtin_amdgcn_mfma_f32_16x16x32_bf16(a1[f][1], b0[j][1], acc[4 + f][j], 0, 0, 0);
      }
    __builtin_amdgcn_s_setprio(0);
    asm volatile("s_barrier" ::: "memory");

    // ---- P3: read B[qn1]; stage A0(k+2)
    #pragma unroll
    for (int j = 0; j < QN; j++) { b1[j][0] = rdB(Bb_, QN + j, 0); b1[j][1] = rdB(Bb_, QN + j, 1); }
    stageA(k2, 0, buf);
    asm volatile("s_barrier" ::: "memory");
    __builtin_amdgcn_s_setprio(1);
    #pragma unroll
    for (int f = 0; f < 4; f++)
      #pragma unroll
      for (int j = 0; j < QN; j++) {
        acc[4 + f][QN + j] = __builtin_amdgcn_mfma_f32_16x16x32_bf16(a1[f][0], b1[j][0], acc[4 + f][QN + j], 0, 0, 0);
        acc[4 + f][QN + j] = __builtin_amdgcn_mfma_f32_16x16x32_bf16(a1[f][1], b1[j][1], acc[4 + f][QN + j], 0, 0, 0);
      }
    __builtin_amdgcn_s_setprio(0);
    asm volatile("s_barrier" ::: "memory");

    // ---- P4: stage A1(k+2); counted vmcnt(4) (2 half-tiles stay in flight)
    stageA(k2, 1, buf);
    asm volatile("s_barrier" ::: "memory");
    __builtin_amdgcn_s_setprio(1);
    #pragma unroll
    for (int f = 0; f < 4; f++)
      #pragma unroll
      for (int j = 0; j < QN; j++) {
        acc[f][QN + j] = __builtin_amdgcn_mfma_f32_16x16x32_bf16(a0[f][0], b1[j][0], acc[f][QN + j], 0, 0, 0);
        acc[f][QN + j] = __builtin_amdgcn_mfma_f32_16x16x32_bf16(a0[f][1], b1[j][1], acc[f][QN + j], 0, 0, 0);
      }
    __builtin_amdgcn_s_setprio(0);
    asm volatile("s_waitcnt vmcnt(4)\n\ts_barrier" ::: "memory");
  };

  for (int k = 0; k < NT; k += 2) {
    ktile(k, 0);
    ktile(k + 1, 1);
  }

  // epilogue
  #pragma unroll
  for (int f = 0; f < 8; f++) {
    int row = m0 + wm * 128 + f * 16 + lg * 4;
    #pragma unroll
    for (int j = 0; j < NREP; j++) {
      int col = n0 + bstart + j * 16 + lc;
      float bv = bias[col];
      #pragma unroll
      for (int t2 = 0; t2 < 4; t2++) {
        float v = acc[f][j][t2] + bv;
        if (RELU) v = fmaxf(v, 0.f);
        if (BF16OUT) ((u16*)Cp)[(size_t)(row + t2) * N + col] = f2b(v);
        else         ((float*)Cp)[(size_t)(row + t2) * N + col] = v;
      }
    }
  }
}

// ---------------- flash attention (strict causal, kq_same) ----------------
__global__ __launch_bounds__(256) void attn_kernel(const u16* __restrict__ QK,
                                                   const u16* __restrict__ V,
                                                   u16* __restrict__ CTX) {
  __shared__ __attribute__((aligned(16))) u16 Qs[64 * 64];
  __shared__ __attribute__((aligned(16))) u16 Ks[64 * 64];
  __shared__ __attribute__((aligned(16))) u16 VTs[64 * 72];
  __shared__ __attribute__((aligned(16))) u16 Ps[4][16 * 72];
  const int qt = blockIdx.x, bh = blockIdx.y;
  const int b = bh >> 4, h = bh & 15;
  const char* Qg = (const char*)(QK + (size_t)b * SLEN * DMODEL + h * DHEAD);
  const char* Vg = (const char*)(V + (size_t)b * SLEN * DMODEL + h * DHEAD);
  const int tid = threadIdx.x, wave = tid >> 6, lane = tid & 63;
  const int lg = lane >> 4, lc = lane & 15;

  #pragma unroll
  for (int c = 0; c < 2; c++) {
    int o = wave * 1024 + c * 4096 + lane * 16;
    int row = o >> 7, colb = o & 127;
    gl_lds16(Qg + (size_t)(qt * 64 + row) * (DMODEL * 2) + colb, (char*)Qs + wave * 1024 + c * 4096);
  }

  float m_run[4], l_run[4];
  f32x4 zero4 = {0.f, 0.f, 0.f, 0.f};
  f32x4 acc_o[4];
  #pragma unroll
  for (int r = 0; r < 4; r++) { m_run[r] = -1e30f; l_run[r] = 0.f; }
  #pragma unroll
  for (int n = 0; n < 4; n++) acc_o[n] = zero4;

  for (int kt = 0; kt <= qt; kt++) {
    __syncthreads();
    #pragma unroll
    for (int c = 0; c < 2; c++) {
      int o = wave * 1024 + c * 4096 + lane * 16;
      int row = o >> 7, colb = o & 127;
      gl_lds16(Qg + (size_t)(kt * 64 + row) * (DMODEL * 2) + colb, (char*)Ks + wave * 1024 + c * 4096);
    }
    {
      int s = tid >> 2, c0 = (tid & 3) * 16;
      const u16* vr = (const u16*)(Vg + (size_t)(kt * 64 + s) * (DMODEL * 2)) + c0;
      uint4 u0 = *(const uint4*)vr;
      uint4 u1 = *(const uint4*)(vr + 8);
      u16 e[16];
      *(uint4*)&e[0] = u0; *(uint4*)&e[8] = u1;
      #pragma unroll
      for (int j = 0; j < 16; j++) VTs[(c0 + j) * 72 + s] = e[j];
    }
    __syncthreads();

    f32x4 sc[4];
    #pragma unroll
    for (int n = 0; n < 4; n++) sc[n] = zero4;
    #pragma unroll
    for (int k0 = 0; k0 < 64; k0 += 32) {
      bf16x8 aq = *(const bf16x8*)&Qs[(wave * 16 + lc) * 64 + k0 + lg * 8];
      #pragma unroll
      for (int n = 0; n < 4; n++) {
        bf16x8 bk_ = *(const bf16x8*)&Ks[(n * 16 + lc) * 64 + k0 + lg * 8];
        sc[n] = __builtin_amdgcn_mfma_f32_16x16x32_bf16(aq, bk_, sc[n], 0, 0, 0);
      }
    }

    float pm[4][4], rmax[4];
    #pragma unroll
    for (int r = 0; r < 4; r++) rmax[r] = -1e30f;
    #pragma unroll
    for (int n = 0; n < 4; n++)
      #pragma unroll
      for (int r = 0; r < 4; r++) {
        int qg = qt * 64 + wave * 16 + lg * 4 + r;
        int kg = kt * 64 + n * 16 + lc;
        float s_ = (kg < qg) ? sc[n][r] * 0.125f : -1e30f;
        pm[n][r] = s_;
        rmax[r] = fmaxf(rmax[r], s_);
      }
    #pragma unroll
    for (int d = 1; d < 16; d <<= 1)
      #pragma unroll
      for (int r = 0; r < 4; r++) rmax[r] = fmaxf(rmax[r], __shfl_xor(rmax[r], d, 64));
    float corr[4];
    #pragma unroll
    for (int r = 0; r < 4; r++) {
      float mn = fmaxf(m_run[r], rmax[r]);
      corr[r] = __expf(m_run[r] - mn);
      m_run[r] = mn;
    }
    float rsum[4] = {0.f, 0.f, 0.f, 0.f};
    #pragma unroll
    for (int n = 0; n < 4; n++)
      #pragma unroll
      for (int r = 0; r < 4; r++) {
        float p = __expf(pm[n][r] - m_run[r]);
        pm[n][r] = p; rsum[r] += p;
      }
    #pragma unroll
    for (int d = 1; d < 16; d <<= 1)
      #pragma unroll
      for (int r = 0; r < 4; r++) rsum[r] += __shfl_xor(rsum[r], d, 64);
    #pragma unroll
    for (int r = 0; r < 4; r++) l_run[r] = l_run[r] * corr[r] + rsum[r];
    #pragma unroll
    for (int n = 0; n < 4; n++)
      #pragma unroll
      for (int r = 0; r < 4; r++) acc_o[n][r] *= corr[r];

    #pragma unroll
    for (int n = 0; n < 4; n++)
      #pragma unroll
      for (int r = 0; r < 4; r++) Ps[wave][(lg * 4 + r) * 72 + n * 16 + lc] = f2b(pm[n][r]);
    __asm__ volatile("s_waitcnt lgkmcnt(0)" ::: "memory");
    #pragma unroll
    for (int k0 = 0; k0 < 64; k0 += 32) {
      bf16x8 ap = *(const bf16x8*)&Ps[wave][lc * 72 + k0 + lg * 8];
      #pragma unroll
      for (int n = 0; n < 4; n++) {
        bf16x8 bv_ = *(const bf16x8*)&VTs[(n * 16 + lc) * 72 + k0 + lg * 8];
        acc_o[n] = __builtin_amdgcn_mfma_f32_16x16x32_bf16(ap, bv_, acc_o[n], 0, 0, 0);
      }
    }
  }

  #pragma unroll
  for (int n = 0; n < 4; n++)
    #pragma unroll
    for (int r = 0; r < 4; r++) {
      int sq = qt * 64 + wave * 16 + lg * 4 + r;
      float v = (sq == 0) ? 0.f : acc_o[n][r] / l_run[r];
      CTX[((size_t)b * SLEN + sq) * DMODEL + h * DHEAD + n * 16 + lc] = f2b(v);
    }
}

// ---------------- fused residual + LayerNorm ----------------
__global__ __launch_bounds__(256) void ln_kernel(const float* __restrict__ tmp,
                                                 float* __restrict__ x,
                                                 u16* __restrict__ xb,
                                                 const float* __restrict__ gw,
                                                 const float* __restrict__ bw) {
  __shared__ float red[4], red2[4];
  const int row = blockIdx.x, t = threadIdx.x;
  const size_t base = (size_t)row * DMODEL;
  float v[4];
  #pragma unroll
  for (int i = 0; i < 4; i++) v[i] = x[base + t + i * 256] + tmp[base + t + i * 256];
  float s = v[0] + v[1] + v[2] + v[3];
  #pragma unroll
  for (int d = 1; d < 64; d <<= 1) s += __shfl_xor(s, d, 64);
  if ((t & 63) == 0) red[t >> 6] = s;
  __syncthreads();
  float mean = (red[0] + red[1] + red[2] + red[3]) * (1.f / DMODEL);
  float q2 = 0.f;
  #pragma unroll
  for (int i = 0; i < 4; i++) { float d_ = v[i] - mean; q2 += d_ * d_; }
  #pragma unroll
  for (int d = 1; d < 64; d <<= 1) q2 += __shfl_xor(q2, d, 64);
  if ((t & 63) == 0) red2[t >> 6] = q2;
  __syncthreads();
  float var = (red2[0] + red2[1] + red2[2] + red2[3]) * (1.f / DMODEL);
  float rs = rsqrtf(var + 1e-5f);
  #pragma unroll
  for (int i = 0; i < 4; i++) {
    int col = t + i * 256;
    float o = (v[i] - mean) * rs * gw[col] + bw[col];
    x[base + col] = o;
    xb[base + col] = f2b(o);
  }
}

__global__ __launch_bounds__(256) void copy_f4(const float4* __restrict__ src, float4* __restrict__ dst) {
  int i = blockIdx.x * 256 + threadIdx.x;
  dst[i] = src[i];
}

extern "C" void kernel_launch(void* const* d_in, const int* in_sizes, int n_in,
                              void* d_out, int out_size, void* d_ws, size_t ws_size,
                              hipStream_t stream) {
  (void)in_sizes; (void)n_in; (void)out_size; (void)ws_size;
  const float* q    = (const float*)d_in[0];
  const float* qa   = (const float*)d_in[1];
  const float* pe   = (const float*)d_in[2];
  const float* Wk   = (const float*)d_in[3];
  const float* bk   = (const float*)d_in[4];
  const float* Wv   = (const float*)d_in[5];
  const float* bv   = (const float*)d_in[6];
  const float* Wo   = (const float*)d_in[7];
  const float* bo   = (const float*)d_in[8];
  const float* ln1g = (const float*)d_in[9];
  const float* ln1b = (const float*)d_in[10];
  const float* W1   = (const float*)d_in[11];
  const float* b1   = (const float*)d_in[12];
  const float* W2   = (const float*)d_in[13];
  const float* b2   = (const float*)d_in[14];
  const float* ln2g = (const float*)d_in[15];
  const float* ln2b = (const float*)d_in[16];

  char* w = (char*)d_ws;
  float* x_f32 = (float*)w; w += (size_t)ROWS * DMODEL * 4;
  u16* xb   = (u16*)w; w += (size_t)ROWS * DMODEL * 2;
  u16* yb   = (u16*)w; w += (size_t)ROWS * DMODEL * 2;
  u16* qkb  = (u16*)w; w += (size_t)ROWS * DMODEL * 2;
  u16* vb   = (u16*)w; w += (size_t)ROWS * DMODEL * 2;
  u16* ctxb = (u16*)w; w += (size_t)ROWS * DMODEL * 2;
  u16* ffnb = (u16*)w; w += (size_t)ROWS * FDIM * 2;
  u16* WkT  = (u16*)w; w += (size_t)DMODEL * DMODEL * 2;
  u16* WvT  = (u16*)w; w += (size_t)DMODEL * DMODEL * 2;
  u16* WoT  = (u16*)w; w += (size_t)DMODEL * DMODEL * 2;
  u16* W1T  = (u16*)w; w += (size_t)DMODEL * FDIM * 2;
  u16* W2T  = (u16*)w; w += (size_t)DMODEL * FDIM * 2;
  float* tmpf = (float*)qkb;  // alias qkb+vb (both dead when tmpf is written)

  prep_kernel<<<ROWS * DMODEL / 4 / 256, 256, 0, stream>>>(
      (const float4*)q, (const float4*)qa, (const float4*)pe, (float4*)x_f32, xb, yb);

  for (int l = 0; l < NLAYER; l++) {
    transpose_f2b<<<dim3(32, 32), 256, 0, stream>>>(Wk + (size_t)l * DMODEL * DMODEL, WkT, DMODEL, DMODEL);
    transpose_f2b<<<dim3(32, 32), 256, 0, stream>>>(Wv + (size_t)l * DMODEL * DMODEL, WvT, DMODEL, DMODEL);
    transpose_f2b<<<dim3(32, 32), 256, 0, stream>>>(Wo + (size_t)l * DMODEL * DMODEL, WoT, DMODEL, DMODEL);
    transpose_f2b<<<dim3(128, 32), 256, 0, stream>>>(W1 + (size_t)l * DMODEL * FDIM, W1T, DMODEL, FDIM);
    transpose_f2b<<<dim3(32, 128), 256, 0, stream>>>(W2 + (size_t)l * FDIM * DMODEL, W2T, FDIM, DMODEL);

    gemm8p<128, false, true><<<dim3(DMODEL / 128, ROWS / 256), 512, 0, stream>>>(
        xb, WkT, bk + l * DMODEL, qkb, ROWS, DMODEL, DMODEL);
    gemm8p<128, false, true><<<dim3(DMODEL / 128, ROWS / 256), 512, 0, stream>>>(
        yb, WvT, bv + l * DMODEL, vb, ROWS, DMODEL, DMODEL);
    attn_kernel<<<dim3(SLEN / 64, BDIM * NHEAD), 256, 0, stream>>>(qkb, vb, ctxb);
    gemm8p<128, false, false><<<dim3(DMODEL / 128, ROWS / 256), 512, 0, stream>>>(
        ctxb, WoT, bo + l * DMODEL, tmpf, ROWS, DMODEL, DMODEL);
    ln_kernel<<<ROWS, 256, 0, stream>>>(tmpf, x_f32, xb, ln1g + l * DMODEL, ln1b + l * DMODEL);
    gemm8p<256, true, true><<<dim3(FDIM / 256, ROWS / 256), 512, 0, stream>>>(
        xb, W1T, b1 + l * FDIM, ffnb, ROWS, FDIM, DMODEL);
    gemm8p<128, false, false><<<dim3(DMODEL / 128, ROWS / 256), 512, 0, stream>>>(
        ffnb, W2T, b2 + l * DMODEL, tmpf, ROWS, DMODEL, FDIM);
    ln_kernel<<<ROWS, 256, 0, stream>>>(tmpf, x_f32, xb, ln2g + l * DMODEL, ln2b + l * DMODEL);
  }
  copy_f4<<<ROWS * DMODEL / 4 / 256, 256, 0, stream>>>((const float4*)x_f32, (float4*)d_out);
}